// Round 1
// baseline (692.486 us; speedup 1.0000x reference)
//
#include <hip/hip_runtime.h>
#include <cstdint>

// LatentFactorPooling on MI355X.
// x: (64,256,64,44) fp32, basis: (4,16,256) fp32.
// out: tokens (64,256,64) fp32 then pres (64,64) fp32.
//
// Workspace layout (floats):
//   lbn_ws    [16384)            normalized basis, layout [g][c][k]
//   invden_ws [16384,20480)      1/max(sum_p supp,1e-6) per (s,k)
//   presraw   [20480,24576)      unnormalized presence per (s,k)
//   supp_ws   [24576,+2883584)   supp, layout [s][k][p] (s=n*4+g, p=704)
// total 11.6 MB.

#define C_ 256
#define W_ 44
#define P_ 704          // 16*44 positions per stripe
#define CH_STRIDE 2816  // 64*44
#define NB_STRIDE 720896 // 256*2816
#define TOPK_ 88
#define GATE_ 0.05f
#define EPS_ 1e-6f

// ---------------- kernel A: normalize latent basis ----------------
__global__ __launch_bounds__(256) void k_norm_basis(const float* __restrict__ lb,
                                                    float* __restrict__ lbn) {
  int gk = blockIdx.x;           // g*16+k
  int t = threadIdx.x;           // channel
  float v = lb[gk * 256 + t];
  float ss = v * v;
  #pragma unroll
  for (int off = 32; off >= 1; off >>= 1) ss += __shfl_xor(ss, off);
  __shared__ float red[4];
  if ((t & 63) == 0) red[t >> 6] = ss;
  __syncthreads();
  float tot = red[0] + red[1] + red[2] + red[3];
  float scale = 1.f / fmaxf(sqrtf(tot), 1e-12f);
  int g = gk >> 4, k = gk & 15;
  lbn[((g * 256 + t) << 4) + k] = v * scale;   // [g][c][k]
}

// ---------------- kernel B: routing (one block per stripe) ----------------
// 704 threads: cg = tid/352 owns 128 channels; t2 = tid%352 owns 2 positions
// (row y = t2/22, x = (t2%22)*2). Streams x once. Raw dots are pooled AFTER
// channel accumulation (pool commutes with the dot); only ||pooled||^2 needs
// per-channel separable pooling (row sums in registers, vertical via LDS).
__global__ __launch_bounds__(704) void k_route(const float* __restrict__ x,
                                               const float* __restrict__ lbn,
                                               float* __restrict__ supp_ws,
                                               float* __restrict__ invden_ws) {
  __shared__ float lbn_l[4096];        // [c][k]
  __shared__ float rbuf_l[8 * 704];    // [buf][pairslot][cg][704] row sums
  __shared__ float rawdot_l[704 * 16]; // [p][k], later reread for pooling
  __shared__ float en_l[704];
  __shared__ float pn_l[704];
  __shared__ float redA[16];
  __shared__ float redB[16];
  __shared__ float red2[11 * 16];

  const int tid = threadIdx.x;
  const int s = blockIdx.x;
  const int n = s >> 2, g = s & 3;

  for (int i = tid; i < 4096; i += 704) lbn_l[i] = lbn[(g << 12) + i];
  __syncthreads();

  const int cg = tid / 352;
  const int t2 = tid % 352;
  const int y = t2 / 22;
  const int xi = t2 % 22;
  const int xp = xi * 2;
  const int p0i = y * 44 + xp;

  const float* xs = x + (size_t)n * NB_STRIDE + g * P_ + y * 44 + xp;

  float rd0[16], rd1[16];
  #pragma unroll
  for (int k = 0; k < 16; k++) { rd0[k] = 0.f; rd1[k] = 0.f; }
  float sq0 = 0.f, sq1 = 0.f, pn0 = 0.f, pn1 = 0.f;
  int buf = 0;

  for (int ci = 0; ci < 128; ci += 2) {
    const int c0 = cg * 128 + ci;
    const float* pa = xs + (size_t)c0 * CH_STRIDE;
    const float* pb = pa + CH_STRIDE;
    float2 va = *(const float2*)pa;
    float2 vb = *(const float2*)pb;
    float vaL = (xi > 0)  ? pa[-1] : 0.f;
    float vaR = (xi < 21) ? pa[2]  : 0.f;
    float vbL = (xi > 0)  ? pb[-1] : 0.f;
    float vbR = (xi < 21) ? pb[2]  : 0.f;

    float ra0 = vaL + va.x + va.y, ra1 = va.x + va.y + vaR;
    float rb0 = vbL + vb.x + vb.y, rb1 = vb.x + vb.y + vbR;

    sq0 += va.x * va.x + vb.x * vb.x;
    sq1 += va.y * va.y + vb.y * vb.y;

    const float4* w0 = (const float4*)&lbn_l[c0 << 4];
    const float4* w1 = (const float4*)&lbn_l[(c0 + 1) << 4];
    #pragma unroll
    for (int kq = 0; kq < 4; kq++) {
      float4 wa = w0[kq], wb = w1[kq];
      rd0[kq*4+0] += va.x * wa.x + vb.x * wb.x;
      rd1[kq*4+0] += va.y * wa.x + vb.y * wb.x;
      rd0[kq*4+1] += va.x * wa.y + vb.x * wb.y;
      rd1[kq*4+1] += va.y * wa.y + vb.y * wb.y;
      rd0[kq*4+2] += va.x * wa.z + vb.x * wb.z;
      rd1[kq*4+2] += va.y * wa.z + vb.y * wb.z;
      rd0[kq*4+3] += va.x * wa.w + vb.x * wb.w;
      rd1[kq*4+3] += va.y * wa.w + vb.y * wb.w;
    }

    float* rbA = &rbuf_l[((buf * 2 + 0) * 2 + cg) * 704 + p0i];
    float* rbB = &rbuf_l[((buf * 2 + 1) * 2 + cg) * 704 + p0i];
    rbA[0] = ra0; rbA[1] = ra1;
    rbB[0] = rb0; rbB[1] = rb1;
    __syncthreads();

    const float* baseA = &rbuf_l[((buf * 2 + 0) * 2 + cg) * 704];
    const float* baseB = &rbuf_l[((buf * 2 + 1) * 2 + cg) * 704];
    float uA0 = 0.f, uA1 = 0.f, dA0 = 0.f, dA1 = 0.f;
    float uB0 = 0.f, uB1 = 0.f, dB0 = 0.f, dB1 = 0.f;
    if (y > 0)  { uA0 = baseA[p0i - 44]; uA1 = baseA[p0i - 43];
                  uB0 = baseB[p0i - 44]; uB1 = baseB[p0i - 43]; }
    if (y < 15) { dA0 = baseA[p0i + 44]; dA1 = baseA[p0i + 45];
                  dB0 = baseB[p0i + 44]; dB1 = baseB[p0i + 45]; }
    float sA0 = uA0 + ra0 + dA0, sA1 = uA1 + ra1 + dA1;
    float sB0 = uB0 + rb0 + dB0, sB1 = uB1 + rb1 + dB1;
    pn0 += sA0 * sA0 + sB0 * sB0;
    pn1 += sA1 * sA1 + sB1 * sB1;
    buf ^= 1;
  }

  // combine the two channel-group partials (2 writers per position, phased)
  if (cg == 0) {
    #pragma unroll
    for (int k = 0; k < 16; k++) {
      rawdot_l[(p0i << 4) + k] = rd0[k];
      rawdot_l[((p0i + 1) << 4) + k] = rd1[k];
    }
    en_l[p0i] = sq0; en_l[p0i + 1] = sq1;
    pn_l[p0i] = pn0; pn_l[p0i + 1] = pn1;
  }
  __syncthreads();
  if (cg == 1) {
    #pragma unroll
    for (int k = 0; k < 16; k++) {
      rawdot_l[(p0i << 4) + k] += rd0[k];
      rawdot_l[((p0i + 1) << 4) + k] += rd1[k];
    }
    en_l[p0i] += sq0; en_l[p0i + 1] += sq1;
    pn_l[p0i] += pn0; pn_l[p0i + 1] += pn1;
  }
  __syncthreads();

  // ---- epilogue: one thread per position ----
  const int q = tid;
  const int qy = q / 44, qx = q % 44;
  const int wid = tid >> 6, lane = tid & 63;

  float e_raw = en_l[q] * (1.f / 256.f);
  float m = e_raw;
  #pragma unroll
  for (int off = 32; off >= 1; off >>= 1) m = fmaxf(m, __shfl_xor(m, off));
  if (lane == 0) redA[wid] = m;
  __syncthreads();
  if (tid == 0) {
    float mm = redA[0];
    for (int w2 = 1; w2 < 11; w2++) mm = fmaxf(mm, redA[w2]);
    redA[12] = mm;
  }
  __syncthreads();
  float M = fmaxf(redA[12], EPS_);
  float e = e_raw / M;
  float am = (e > GATE_) ? 1.f : 0.f;
  float fb = (e_raw > 0.f) ? 1.f : 0.f;
  float a = am;
  #pragma unroll
  for (int off = 32; off >= 1; off >>= 1) a += __shfl_xor(a, off);
  if (lane == 0) redB[wid] = a;
  __syncthreads();
  if (tid == 0) {
    float sm = 0.f;
    for (int w2 = 0; w2 < 11; w2++) sm += redB[w2];
    redB[12] = sm;
  }
  __syncthreads();
  if (redB[12] <= 0.f) am = fb;

  // pool the raw dots (linearity: pooled.basis == pool(raw.basis)/9)
  float pd[16];
  #pragma unroll
  for (int k = 0; k < 16; k++) pd[k] = 0.f;
  #pragma unroll
  for (int dy = -1; dy <= 1; dy++) {
    int yy = qy + dy;
    if (yy < 0 || yy > 15) continue;
    #pragma unroll
    for (int dx = -1; dx <= 1; dx++) {
      int xx = qx + dx;
      if (xx < 0 || xx > 43) continue;
      const float4* rp = (const float4*)&rawdot_l[(yy * 44 + xx) << 4];
      #pragma unroll
      for (int kq = 0; kq < 4; kq++) {
        float4 vv = rp[kq];
        pd[kq*4+0] += vv.x; pd[kq*4+1] += vv.y;
        pd[kq*4+2] += vv.z; pd[kq*4+3] += vv.w;
      }
    }
  }

  float pnorm = sqrtf(pn_l[q]) * (1.f / 9.f);   // ||pooled||
  float invn = 1.f / fmaxf(pnorm, 1e-12f);
  float scl = invn * (8.f / 9.f);               // /9 pool, /0.125 temp
  float li[16];
  float mx = -1e30f;
  #pragma unroll
  for (int k = 0; k < 16; k++) { li[k] = pd[k] * scl; mx = fmaxf(mx, li[k]); }
  float ssum = 0.f;
  #pragma unroll
  for (int k = 0; k < 16; k++) { li[k] = __expf(li[k] - mx); ssum += li[k]; }
  float rs = am / ssum;
  float supp[16];
  #pragma unroll
  for (int k = 0; k < 16; k++) supp[k] = li[k] * rs;

  float* sbp = supp_ws + (size_t)s * (16 * 704);
  #pragma unroll
  for (int k = 0; k < 16; k++) sbp[k * 704 + q] = supp[k];  // [k][p], coalesced

  // per-k denominators
  #pragma unroll
  for (int k = 0; k < 16; k++) {
    float v = supp[k];
    #pragma unroll
    for (int off = 32; off >= 1; off >>= 1) v += __shfl_xor(v, off);
    if (lane == 0) red2[wid * 16 + k] = v;
  }
  __syncthreads();
  if (tid < 16) {
    float den = 0.f;
    for (int w2 = 0; w2 < 11; w2++) den += red2[w2 * 16 + tid];
    invden_ws[s * 16 + tid] = 1.f / fmaxf(den, EPS_);
  }
}

// ---------------- kernel C: exact top-88 mean via radix select ----------------
__global__ __launch_bounds__(256) void k_topk(const float* __restrict__ supp_ws,
                                              float* __restrict__ presraw) {
  const int blk = blockIdx.x;   // s*16+k
  const int t = threadIdx.x;
  const float* v = supp_ws + (size_t)blk * 704;
  const bool h2 = (t < 192);
  uint32_t key0 = __float_as_uint(v[t]);        // supp >= 0 => bits monotone
  uint32_t key1 = __float_as_uint(v[t + 256]);
  uint32_t key2 = h2 ? __float_as_uint(v[t + 512]) : 0u;

  __shared__ uint32_t hist[256];
  __shared__ uint32_t bc0, bc1;
  uint32_t prefix = 0, remaining = TOPK_;

  for (int b = 3; b >= 0; b--) {
    hist[t] = 0u;
    __syncthreads();
    const int shift = b * 8;
    uint32_t mhi = (b == 3) ? 0u : (0xFFFFFFFFu << (shift + 8));
    if ((key0 & mhi) == (prefix & mhi)) atomicAdd(&hist[(key0 >> shift) & 255u], 1u);
    if ((key1 & mhi) == (prefix & mhi)) atomicAdd(&hist[(key1 >> shift) & 255u], 1u);
    if (h2 && ((key2 & mhi) == (prefix & mhi))) atomicAdd(&hist[(key2 >> shift) & 255u], 1u);
    __syncthreads();
    if (t == 0) {
      uint32_t cum = 0, bin = 0;
      for (int i = 255; i >= 0; i--) {
        uint32_t c = hist[i];
        if (cum + c >= remaining) { bin = (uint32_t)i; break; }
        cum += c;
      }
      bc0 = prefix | (bin << shift);
      bc1 = remaining - cum;
    }
    __syncthreads();
    prefix = bc0; remaining = bc1;
    __syncthreads();
  }

  float tf = __uint_as_float(prefix);           // value of 88th largest
  float sgt = 0.f;
  uint32_t cgt = 0;
  if (key0 > prefix) { sgt += __uint_as_float(key0); cgt++; }
  if (key1 > prefix) { sgt += __uint_as_float(key1); cgt++; }
  if (h2 && key2 > prefix) { sgt += __uint_as_float(key2); cgt++; }
  #pragma unroll
  for (int off = 32; off >= 1; off >>= 1) {
    sgt += __shfl_xor(sgt, off);
    cgt += __shfl_xor(cgt, off);
  }
  __shared__ float rsx[4];
  __shared__ uint32_t rcx[4];
  if ((t & 63) == 0) { rsx[t >> 6] = sgt; rcx[t >> 6] = cgt; }
  __syncthreads();
  if (t == 0) {
    float stot = rsx[0] + rsx[1] + rsx[2] + rsx[3];
    uint32_t ctot = rcx[0] + rcx[1] + rcx[2] + rcx[3];
    float top = stot + (float)(TOPK_ - ctot) * tf;  // ties (incl. zeros) exact
    presraw[blk] = top * (1.f / (float)TOPK_);
  }
}

// ---------------- kernel 3: tokens GEMM (supp^T @ feat) ----------------
// block = (stripe, p-chunk of 176); 128 threads, 2 channels each, all 16 k.
// supp broadcast from LDS (wave-uniform b128 reads), x streamed float4/row.
__global__ __launch_bounds__(128) void k_tokens(const float* __restrict__ x,
                                                const float* __restrict__ supp_ws,
                                                const float* __restrict__ invden_ws,
                                                float* __restrict__ out) {
  __shared__ float supp_l[176 * 20];   // stride 20: b128-aligned, conflict-poor
  __shared__ float idv_l[16];
  const int tid = threadIdx.x;
  const int bid = blockIdx.x;
  const int s = bid >> 2, chunk = bid & 3;
  const int n = s >> 2, g = s & 3;
  const int q0 = chunk * 176;

  if (tid < 16) idv_l[tid] = invden_ws[s * 16 + tid];
  const float* sb = supp_ws + (size_t)s * (16 * 704) + q0;
  for (int idx = tid; idx < 2816; idx += 128) {
    int k = idx / 176, ql = idx % 176;
    supp_l[ql * 20 + k] = sb[k * 704 + ql];
  }
  __syncthreads();

  const float* r0 = x + (size_t)(n * 256 + tid) * CH_STRIDE + g * P_ + q0;
  const float* r1 = r0 + (size_t)128 * CH_STRIDE;
  float acc0[16], acc1[16];
  #pragma unroll
  for (int k = 0; k < 16; k++) { acc0[k] = 0.f; acc1[k] = 0.f; }

  for (int pv = 0; pv < 44; pv++) {
    float4 f0 = ((const float4*)r0)[pv];
    float4 f1 = ((const float4*)r1)[pv];
    float f0a[4] = {f0.x, f0.y, f0.z, f0.w};
    float f1a[4] = {f1.x, f1.y, f1.z, f1.w};
    #pragma unroll
    for (int j = 0; j < 4; j++) {
      const float* sp = &supp_l[(pv * 4 + j) * 20];
      float a0 = f0a[j], a1 = f1a[j];
      #pragma unroll
      for (int kq = 0; kq < 4; kq++) {
        float4 sv = *(const float4*)(sp + kq * 4);
        acc0[kq*4+0] += a0 * sv.x; acc1[kq*4+0] += a1 * sv.x;
        acc0[kq*4+1] += a0 * sv.y; acc1[kq*4+1] += a1 * sv.y;
        acc0[kq*4+2] += a0 * sv.z; acc1[kq*4+2] += a1 * sv.z;
        acc0[kq*4+3] += a0 * sv.w; acc1[kq*4+3] += a1 * sv.w;
      }
    }
  }

  size_t ob0 = (size_t)(n * 256 + tid) * 64 + g * 16;
  size_t ob1 = (size_t)(n * 256 + tid + 128) * 64 + g * 16;
  #pragma unroll
  for (int k = 0; k < 16; k++) {
    atomicAdd(&out[ob0 + k], acc0[k] * idv_l[k]);
    atomicAdd(&out[ob1 + k], acc1[k] * idv_l[k]);
  }
}

// ---------------- kernel D: presence normalization ----------------
__global__ __launch_bounds__(64) void k_pres(const float* __restrict__ presraw,
                                             float* __restrict__ out) {
  const int n = blockIdx.x, t = threadIdx.x;
  float v = presraw[n * 64 + t];
  float ssum = v;
  #pragma unroll
  for (int off = 32; off >= 1; off >>= 1) ssum += __shfl_xor(ssum, off);
  out[1048576 + n * 64 + t] = v / fmaxf(ssum, EPS_);
}

extern "C" void kernel_launch(void* const* d_in, const int* in_sizes, int n_in,
                              void* d_out, int out_size, void* d_ws, size_t ws_size,
                              hipStream_t stream) {
  (void)in_sizes; (void)n_in; (void)out_size; (void)ws_size;
  const float* x  = (const float*)d_in[0];
  const float* lb = (const float*)d_in[1];
  float* out = (float*)d_out;
  float* ws = (float*)d_ws;
  float* lbn_ws     = ws;            // 16384 floats
  float* invden_ws  = ws + 16384;    // 4096
  float* presraw_ws = ws + 20480;    // 4096
  float* supp_ws    = ws + 24576;    // 2883584  (ws total ~11.6 MB)

  // tokens are accumulated with atomics; d_out is poisoned before each run
  hipMemsetAsync(d_out, 0, (size_t)1048576 * sizeof(float), stream);

  k_norm_basis<<<64, 256, 0, stream>>>(lb, lbn_ws);
  k_route<<<256, 704, 0, stream>>>(x, lbn_ws, supp_ws, invden_ws);
  k_topk<<<4096, 256, 0, stream>>>(supp_ws, presraw_ws);
  k_tokens<<<1024, 128, 0, stream>>>(x, supp_ws, invden_ws, out);
  k_pres<<<64, 64, 0, stream>>>(presraw_ws, out);
}

// Round 2
// 393.761 us; speedup vs baseline: 1.7586x; 1.7586x over previous
//
#include <hip/hip_runtime.h>
#include <cstdint>

// LatentFactorPooling on MI355X.
// x: (64,256,64,44) fp32, basis: (4,16,256) fp32.
// out: tokens (64,256,64) fp32 then pres (64,64) fp32.
//
// Workspace layout (floats):
//   lbn_ws     [0,16384)             normalized basis, [g][c][k]
//   invden_ws  [16384,20480)         1/max(sum_p supp,1e-6) per (s,k)
//   presraw    [20480,24576)         unnormalized presence per (s,k)
//   supp_kp    [24576,2908160)       supp, [s][k][p]  (topk kernel)
//   supp_pk    [2908160,5791744)     supp, [s][p][k]  (tokens kernel)
// total ~23.2 MB.

#define C_ 256
#define W_ 44
#define P_ 704          // 16*44 positions per stripe
#define CH_STRIDE 2816  // 64*44
#define NB_STRIDE 720896 // 256*2816
#define TOPK_ 88
#define GATE_ 0.05f
#define EPS_ 1e-6f

// ---------------- kernel A: normalize latent basis ----------------
__global__ __launch_bounds__(256) void k_norm_basis(const float* __restrict__ lb,
                                                    float* __restrict__ lbn) {
  int gk = blockIdx.x;           // g*16+k
  int t = threadIdx.x;           // channel
  float v = lb[gk * 256 + t];
  float ss = v * v;
  #pragma unroll
  for (int off = 32; off >= 1; off >>= 1) ss += __shfl_xor(ss, off);
  __shared__ float red[4];
  if ((t & 63) == 0) red[t >> 6] = ss;
  __syncthreads();
  float tot = red[0] + red[1] + red[2] + red[3];
  float scale = 1.f / fmaxf(sqrtf(tot), 1e-12f);
  int g = gk >> 4, k = gk & 15;
  lbn[((g * 256 + t) << 4) + k] = v * scale;   // [g][c][k]
}

// ---------------- kernel B: routing (one block per stripe) ----------------
__global__ __launch_bounds__(704) void k_route(const float* __restrict__ x,
                                               const float* __restrict__ lbn,
                                               float* __restrict__ supp_kp,
                                               float* __restrict__ supp_pk,
                                               float* __restrict__ invden_ws) {
  __shared__ float lbn_l[4096];        // [c][k]
  __shared__ float rbuf_l[8 * 704];    // [buf][pairslot][cg][704] row sums
  __shared__ float rawdot_l[704 * 16]; // [p][k], later reread for pooling
  __shared__ float en_l[704];
  __shared__ float pn_l[704];
  __shared__ float redA[16];
  __shared__ float redB[16];
  __shared__ float red2[11 * 16];

  const int tid = threadIdx.x;
  const int s = blockIdx.x;
  const int n = s >> 2, g = s & 3;

  for (int i = tid; i < 4096; i += 704) lbn_l[i] = lbn[(g << 12) + i];
  __syncthreads();

  const int cg = tid / 352;
  const int t2 = tid % 352;
  const int y = t2 / 22;
  const int xi = t2 % 22;
  const int xp = xi * 2;
  const int p0i = y * 44 + xp;

  const float* xs = x + (size_t)n * NB_STRIDE + g * P_ + y * 44 + xp;

  float rd0[16], rd1[16];
  #pragma unroll
  for (int k = 0; k < 16; k++) { rd0[k] = 0.f; rd1[k] = 0.f; }
  float sq0 = 0.f, sq1 = 0.f, pn0 = 0.f, pn1 = 0.f;
  int buf = 0;

  for (int ci = 0; ci < 128; ci += 2) {
    const int c0 = cg * 128 + ci;
    const float* pa = xs + (size_t)c0 * CH_STRIDE;
    const float* pb = pa + CH_STRIDE;
    float2 va = *(const float2*)pa;
    float2 vb = *(const float2*)pb;
    float vaL = (xi > 0)  ? pa[-1] : 0.f;
    float vaR = (xi < 21) ? pa[2]  : 0.f;
    float vbL = (xi > 0)  ? pb[-1] : 0.f;
    float vbR = (xi < 21) ? pb[2]  : 0.f;

    float ra0 = vaL + va.x + va.y, ra1 = va.x + va.y + vaR;
    float rb0 = vbL + vb.x + vb.y, rb1 = vb.x + vb.y + vbR;

    sq0 += va.x * va.x + vb.x * vb.x;
    sq1 += va.y * va.y + vb.y * vb.y;

    const float4* w0 = (const float4*)&lbn_l[c0 << 4];
    const float4* w1 = (const float4*)&lbn_l[(c0 + 1) << 4];
    #pragma unroll
    for (int kq = 0; kq < 4; kq++) {
      float4 wa = w0[kq], wb = w1[kq];
      rd0[kq*4+0] += va.x * wa.x + vb.x * wb.x;
      rd1[kq*4+0] += va.y * wa.x + vb.y * wb.x;
      rd0[kq*4+1] += va.x * wa.y + vb.x * wb.y;
      rd1[kq*4+1] += va.y * wa.y + vb.y * wb.y;
      rd0[kq*4+2] += va.x * wa.z + vb.x * wb.z;
      rd1[kq*4+2] += va.y * wa.z + vb.y * wb.z;
      rd0[kq*4+3] += va.x * wa.w + vb.x * wb.w;
      rd1[kq*4+3] += va.y * wa.w + vb.y * wb.w;
    }

    float* rbA = &rbuf_l[((buf * 2 + 0) * 2 + cg) * 704 + p0i];
    float* rbB = &rbuf_l[((buf * 2 + 1) * 2 + cg) * 704 + p0i];
    rbA[0] = ra0; rbA[1] = ra1;
    rbB[0] = rb0; rbB[1] = rb1;
    __syncthreads();

    const float* baseA = &rbuf_l[((buf * 2 + 0) * 2 + cg) * 704];
    const float* baseB = &rbuf_l[((buf * 2 + 1) * 2 + cg) * 704];
    float uA0 = 0.f, uA1 = 0.f, dA0 = 0.f, dA1 = 0.f;
    float uB0 = 0.f, uB1 = 0.f, dB0 = 0.f, dB1 = 0.f;
    if (y > 0)  { uA0 = baseA[p0i - 44]; uA1 = baseA[p0i - 43];
                  uB0 = baseB[p0i - 44]; uB1 = baseB[p0i - 43]; }
    if (y < 15) { dA0 = baseA[p0i + 44]; dA1 = baseA[p0i + 45];
                  dB0 = baseB[p0i + 44]; dB1 = baseB[p0i + 45]; }
    float sA0 = uA0 + ra0 + dA0, sA1 = uA1 + ra1 + dA1;
    float sB0 = uB0 + rb0 + dB0, sB1 = uB1 + rb1 + dB1;
    pn0 += sA0 * sA0 + sB0 * sB0;
    pn1 += sA1 * sA1 + sB1 * sB1;
    buf ^= 1;
  }

  // combine the two channel-group partials (2 writers per position, phased)
  if (cg == 0) {
    #pragma unroll
    for (int k = 0; k < 16; k++) {
      rawdot_l[(p0i << 4) + k] = rd0[k];
      rawdot_l[((p0i + 1) << 4) + k] = rd1[k];
    }
    en_l[p0i] = sq0; en_l[p0i + 1] = sq1;
    pn_l[p0i] = pn0; pn_l[p0i + 1] = pn1;
  }
  __syncthreads();
  if (cg == 1) {
    #pragma unroll
    for (int k = 0; k < 16; k++) {
      rawdot_l[(p0i << 4) + k] += rd0[k];
      rawdot_l[((p0i + 1) << 4) + k] += rd1[k];
    }
    en_l[p0i] += sq0; en_l[p0i + 1] += sq1;
    pn_l[p0i] += pn0; pn_l[p0i + 1] += pn1;
  }
  __syncthreads();

  // ---- epilogue: one thread per position ----
  const int q = tid;
  const int qy = q / 44, qx = q % 44;
  const int wid = tid >> 6, lane = tid & 63;

  float e_raw = en_l[q] * (1.f / 256.f);
  float m = e_raw;
  #pragma unroll
  for (int off = 32; off >= 1; off >>= 1) m = fmaxf(m, __shfl_xor(m, off));
  if (lane == 0) redA[wid] = m;
  __syncthreads();
  if (tid == 0) {
    float mm = redA[0];
    for (int w2 = 1; w2 < 11; w2++) mm = fmaxf(mm, redA[w2]);
    redA[12] = mm;
  }
  __syncthreads();
  float M = fmaxf(redA[12], EPS_);
  float e = e_raw / M;
  float am = (e > GATE_) ? 1.f : 0.f;
  float fb = (e_raw > 0.f) ? 1.f : 0.f;
  float a = am;
  #pragma unroll
  for (int off = 32; off >= 1; off >>= 1) a += __shfl_xor(a, off);
  if (lane == 0) redB[wid] = a;
  __syncthreads();
  if (tid == 0) {
    float sm = 0.f;
    for (int w2 = 0; w2 < 11; w2++) sm += redB[w2];
    redB[12] = sm;
  }
  __syncthreads();
  if (redB[12] <= 0.f) am = fb;

  // pool the raw dots (linearity: pooled.basis == pool(raw.basis)/9)
  float pd[16];
  #pragma unroll
  for (int k = 0; k < 16; k++) pd[k] = 0.f;
  #pragma unroll
  for (int dy = -1; dy <= 1; dy++) {
    int yy = qy + dy;
    if (yy < 0 || yy > 15) continue;
    #pragma unroll
    for (int dx = -1; dx <= 1; dx++) {
      int xx = qx + dx;
      if (xx < 0 || xx > 43) continue;
      const float4* rp = (const float4*)&rawdot_l[(yy * 44 + xx) << 4];
      #pragma unroll
      for (int kq = 0; kq < 4; kq++) {
        float4 vv = rp[kq];
        pd[kq*4+0] += vv.x; pd[kq*4+1] += vv.y;
        pd[kq*4+2] += vv.z; pd[kq*4+3] += vv.w;
      }
    }
  }

  float pnorm = sqrtf(pn_l[q]) * (1.f / 9.f);   // ||pooled||
  float invn = 1.f / fmaxf(pnorm, 1e-12f);
  float scl = invn * (8.f / 9.f);               // /9 pool, /0.125 temp
  float li[16];
  float mx = -1e30f;
  #pragma unroll
  for (int k = 0; k < 16; k++) { li[k] = pd[k] * scl; mx = fmaxf(mx, li[k]); }
  float ssum = 0.f;
  #pragma unroll
  for (int k = 0; k < 16; k++) { li[k] = __expf(li[k] - mx); ssum += li[k]; }
  float rs = am / ssum;
  float supp[16];
  #pragma unroll
  for (int k = 0; k < 16; k++) supp[k] = li[k] * rs;

  float* sbp = supp_kp + (size_t)s * (16 * 704);
  #pragma unroll
  for (int k = 0; k < 16; k++) sbp[k * 704 + q] = supp[k];  // [k][p], coalesced

  float* spk = supp_pk + ((size_t)s * 704 + q) * 16;        // [p][k]
  #pragma unroll
  for (int kq = 0; kq < 4; kq++) {
    ((float4*)spk)[kq] = make_float4(supp[kq*4+0], supp[kq*4+1],
                                     supp[kq*4+2], supp[kq*4+3]);
  }

  // per-k denominators
  #pragma unroll
  for (int k = 0; k < 16; k++) {
    float v = supp[k];
    #pragma unroll
    for (int off = 32; off >= 1; off >>= 1) v += __shfl_xor(v, off);
    if (lane == 0) red2[wid * 16 + k] = v;
  }
  __syncthreads();
  if (tid < 16) {
    float den = 0.f;
    for (int w2 = 0; w2 < 11; w2++) den += red2[w2 * 16 + tid];
    invden_ws[s * 16 + tid] = 1.f / fmaxf(den, EPS_);
  }
}

// ---------------- kernel C: exact top-88 mean via radix select ----------------
// parallel suffix-scan version (shfl within wave + 4-wave combine)
__global__ __launch_bounds__(256) void k_topk(const float* __restrict__ supp_kp,
                                              float* __restrict__ presraw) {
  const int blk = blockIdx.x;   // s*16+k
  const int t = threadIdx.x;
  const int lane = t & 63, w = t >> 6;
  const float* v = supp_kp + (size_t)blk * 704;
  const bool h2 = (t < 192);
  uint32_t key0 = __float_as_uint(v[t]);        // supp >= 0 => bits monotone
  uint32_t key1 = __float_as_uint(v[t + 256]);
  uint32_t key2 = h2 ? __float_as_uint(v[t + 512]) : 0u;

  __shared__ uint32_t hist[256];
  __shared__ uint32_t sarr[257];
  __shared__ uint32_t wsum[4];
  __shared__ uint32_t bc0, bc1;
  uint32_t prefix = 0, remaining = TOPK_;

  for (int b = 3; b >= 0; b--) {
    hist[t] = 0u;
    __syncthreads();
    const int shift = b * 8;
    uint32_t mhi = (b == 3) ? 0u : (0xFFFFFFFFu << (shift + 8));
    if ((key0 & mhi) == (prefix & mhi)) atomicAdd(&hist[(key0 >> shift) & 255u], 1u);
    if ((key1 & mhi) == (prefix & mhi)) atomicAdd(&hist[(key1 >> shift) & 255u], 1u);
    if (h2 && ((key2 & mhi) == (prefix & mhi))) atomicAdd(&hist[(key2 >> shift) & 255u], 1u);
    __syncthreads();

    // suffix sum S[t] = sum_{i>=t} hist[i]
    uint32_t val = hist[t];
    #pragma unroll
    for (int off = 1; off < 64; off <<= 1) {
      uint32_t o = (uint32_t)__shfl_down((int)val, off);
      if (lane + off < 64) val += o;
    }
    if (lane == 0) wsum[w] = val;
    __syncthreads();
    uint32_t add = 0;
    for (int w2 = w + 1; w2 < 4; w2++) add += wsum[w2];
    // recompute own suffix-within-wave (val at lane l already is it)
    sarr[t] = val + add;
    if (t == 0) sarr[256] = 0u;
    __syncthreads();
    uint32_t s_t = sarr[t], s_n = sarr[t + 1];
    if (s_t >= remaining && s_n < remaining) {       // unique crossing
      bc0 = prefix | ((uint32_t)t << shift);
      bc1 = remaining - s_n;
    }
    __syncthreads();
    prefix = bc0; remaining = bc1;
    __syncthreads();
  }

  float tf = __uint_as_float(prefix);           // value of 88th largest
  float sgt = 0.f;
  uint32_t cgt = 0;
  if (key0 > prefix) { sgt += __uint_as_float(key0); cgt++; }
  if (key1 > prefix) { sgt += __uint_as_float(key1); cgt++; }
  if (h2 && key2 > prefix) { sgt += __uint_as_float(key2); cgt++; }
  #pragma unroll
  for (int off = 32; off >= 1; off >>= 1) {
    sgt += __shfl_xor(sgt, off);
    cgt += __shfl_xor(cgt, off);
  }
  __shared__ float rsx[4];
  __shared__ uint32_t rcx[4];
  if (lane == 0) { rsx[w] = sgt; rcx[w] = cgt; }
  __syncthreads();
  if (t == 0) {
    float stot = rsx[0] + rsx[1] + rsx[2] + rsx[3];
    uint32_t ctot = rcx[0] + rcx[1] + rcx[2] + rcx[3];
    float top = stot + (float)(TOPK_ - ctot) * tf;  // ties (incl. zeros) exact
    presraw[blk] = top * (1.f / (float)TOPK_);
  }
}

// ---------------- kernel 3: tokens GEMM (supp^T @ feat), LDS-transposed ----------------
// block = stripe (256 blocks x 1024 threads). Tiles of 256ch x 32pos staged in
// LDS (XOR-swizzled, 32KB) with coalesced global loads + register prefetch.
// Thread (c = tid&255, q = tid>>8) accumulates 16 k over its position-quarter;
// supp rows come from wave-uniform scalar loads (readfirstlane-forced).
__global__ __launch_bounds__(1024, 4) void k_tokens(const float* __restrict__ x,
                                                    const float* __restrict__ supp_pk,
                                                    const float* __restrict__ invden,
                                                    float* __restrict__ out) {
  __shared__ float xl[8192];   // 256ch x 32pos, xor-swizzled; reused for reduce
  const int tid = threadIdx.x;
  const int s = blockIdx.x;
  const int n = s >> 2, g = s & 3;
  const int c = tid & 255;
  const int q = tid >> 8;                 // position quarter, uniform per wave
  const int sblk = s * (704 * 16);

  const float* xs = x + (size_t)n * NB_STRIDE + g * P_;

  // loader mapping: two float4 per thread per tile
  const int li0 = tid, li1 = tid + 1024;
  const int lc0 = li0 >> 3, lj0 = li0 & 7;
  const int lc1 = li1 >> 3, lj1 = li1 & 7;
  const float* gp0 = xs + (size_t)lc0 * CH_STRIDE + lj0 * 4;
  const float* gp1 = xs + (size_t)lc1 * CH_STRIDE + lj1 * 4;
  const int wo0 = lc0 * 32 + ((lj0 * 4) ^ ((lc0 & 7) * 4));
  const int wo1 = lc1 * 32 + ((lj1 * 4) ^ ((lc1 & 7) * 4));

  const int sw = (c & 7) * 4;             // read-side xor swizzle
  const int rbase = c * 32;

  float acc[16];
  #pragma unroll
  for (int k = 0; k < 16; k++) acc[k] = 0.f;

  // prologue: tile 0
  float4 r0 = *(const float4*)gp0;
  float4 r1 = *(const float4*)gp1;
  *(float4*)&xl[wo0] = r0;
  *(float4*)&xl[wo1] = r1;
  __syncthreads();

  for (int tt = 0; tt < 22; tt++) {
    const int p0 = tt * 32;
    float4 n0, n1;
    if (tt < 21) {
      n0 = *(const float4*)(gp0 + p0 + 32);
      n1 = *(const float4*)(gp1 + p0 + 32);
    }

    #pragma unroll
    for (int jj = 0; jj < 8; jj += 4) {
      const int pp0 = q * 8 + jj;
      float4 xv = *(const float4*)&xl[rbase + (pp0 ^ sw)];
      float xa[4] = {xv.x, xv.y, xv.z, xv.w};
      #pragma unroll
      for (int dj = 0; dj < 4; dj++) {
        int uofs = __builtin_amdgcn_readfirstlane(sblk + (p0 + pp0 + dj) * 16);
        const float4* sp = (const float4*)(supp_pk + uofs);
        float4 s0 = sp[0], s1 = sp[1], s2 = sp[2], s3 = sp[3];
        float a = xa[dj];
        acc[0]  += a * s0.x; acc[1]  += a * s0.y; acc[2]  += a * s0.z; acc[3]  += a * s0.w;
        acc[4]  += a * s1.x; acc[5]  += a * s1.y; acc[6]  += a * s1.z; acc[7]  += a * s1.w;
        acc[8]  += a * s2.x; acc[9]  += a * s2.y; acc[10] += a * s2.z; acc[11] += a * s2.w;
        acc[12] += a * s3.x; acc[13] += a * s3.y; acc[14] += a * s3.z; acc[15] += a * s3.w;
      }
    }

    __syncthreads();
    if (tt < 21) {
      *(float4*)&xl[wo0] = n0;
      *(float4*)&xl[wo1] = n1;
      __syncthreads();
    }
  }

  // quarter-reduce via LDS (xl reused; all tiles consumed)
  if (q >= 2) {
    float* dst = &xl[((q - 2) * 256 + c) * 16];
    #pragma unroll
    for (int kq = 0; kq < 4; kq++)
      ((float4*)dst)[kq] = make_float4(acc[kq*4], acc[kq*4+1], acc[kq*4+2], acc[kq*4+3]);
  }
  __syncthreads();
  if (q < 2) {
    const float* src = &xl[(q * 256 + c) * 16];
    #pragma unroll
    for (int k = 0; k < 16; k++) acc[k] += src[k];
  }
  __syncthreads();
  if (q == 1) {
    float* dst = &xl[c * 16];
    #pragma unroll
    for (int kq = 0; kq < 4; kq++)
      ((float4*)dst)[kq] = make_float4(acc[kq*4], acc[kq*4+1], acc[kq*4+2], acc[kq*4+3]);
  }
  __syncthreads();
  if (q == 0) {
    const float* src = &xl[c * 16];
    float* op = out + ((size_t)(n * 256 + c) * 64) + g * 16;
    #pragma unroll
    for (int kq = 0; kq < 4; kq++) {
      int u = __builtin_amdgcn_readfirstlane(s * 16 + kq * 4);
      const float4 iv = *(const float4*)(invden + u);
      float4 o;
      o.x = (acc[kq*4+0] + src[kq*4+0]) * iv.x;
      o.y = (acc[kq*4+1] + src[kq*4+1]) * iv.y;
      o.z = (acc[kq*4+2] + src[kq*4+2]) * iv.z;
      o.w = (acc[kq*4+3] + src[kq*4+3]) * iv.w;
      ((float4*)op)[kq] = o;
    }
  }
}

// ---------------- kernel D: presence normalization ----------------
__global__ __launch_bounds__(64) void k_pres(const float* __restrict__ presraw,
                                             float* __restrict__ out) {
  const int n = blockIdx.x, t = threadIdx.x;
  float v = presraw[n * 64 + t];
  float ssum = v;
  #pragma unroll
  for (int off = 32; off >= 1; off >>= 1) ssum += __shfl_xor(ssum, off);
  out[1048576 + n * 64 + t] = v / fmaxf(ssum, EPS_);
}

extern "C" void kernel_launch(void* const* d_in, const int* in_sizes, int n_in,
                              void* d_out, int out_size, void* d_ws, size_t ws_size,
                              hipStream_t stream) {
  (void)in_sizes; (void)n_in; (void)out_size; (void)ws_size;
  const float* x  = (const float*)d_in[0];
  const float* lb = (const float*)d_in[1];
  float* out = (float*)d_out;
  float* ws = (float*)d_ws;
  float* lbn_ws     = ws;              // 16384 floats
  float* invden_ws  = ws + 16384;      // 4096
  float* presraw_ws = ws + 20480;      // 4096
  float* supp_kp_ws = ws + 24576;      // 2883584
  float* supp_pk_ws = ws + 2908160;    // 2883584  (total ~23.2 MB)

  k_norm_basis<<<64, 256, 0, stream>>>(lb, lbn_ws);
  k_route<<<256, 704, 0, stream>>>(x, lbn_ws, supp_kp_ws, supp_pk_ws, invden_ws);
  k_topk<<<4096, 256, 0, stream>>>(supp_kp_ws, presraw_ws);
  k_tokens<<<256, 1024, 0, stream>>>(x, supp_pk_ws, invden_ws, out);
  k_pres<<<64, 64, 0, stream>>>(presraw_ws, out);
}